// Round 6
// baseline (133.788 us; speedup 1.0000x reference)
//
#include <hip/hip_runtime.h>
#include <math.h>

#define N_PTS 20000
#define M_ATM 8000
#define DD    16
#define KK    16
#define HH    33
#define BB    4
#define EPSGN 1e-5f
#define SLOPE 0.2f
#define SLOTS 36   // 36*64 = 2304 candidates/wave >= max batch segment
#define ALL1  0xFFFFFFFFFFFFFFFFull

// packed layout per layer (floats): wx[33][20] | wb[33][16] | wt[33][16]
#define PK_WX   0
#define PK_WB   660
#define PK_WT   1188
#define PK_LAY  1716

// ws layout (bytes)
#define WS_YD    0                       // 8000 * 32 B f64 (-2y0,-2y1,-2y2,|y|^2)
#define WS_SEG   256000                  // 5 ints (+pad)
#define WS_WP    256064                  // 3*1716 floats
#define WS_IDX   276672                  // N*K ints
#define WS_D2    (276672 + 1280000)      // N*K floats

// ---------------- repack: weights + f64 atom table + batch boundaries ----------------
__global__ void repack_kernel(const float* __restrict__ W1, const float* __restrict__ b1,
                              const float* __restrict__ W2,
                              const float* __restrict__ y, const int* __restrict__ yb,
                              float* __restrict__ wp, double* __restrict__ yd,
                              int* __restrict__ seg)
{
    const int tid = blockIdx.x*256 + threadIdx.x;
    const int stride = gridDim.x*256;

    for (int i = tid; i < 3*PK_LAY; i += stride) {
        const int L = i / PK_LAY, r = i % PK_LAY;
        float v;
        if (r < PK_WB) {                    // wx[o][20] = W1a(16) | b1 | w_dist | pad2
            const int o = r / 20, c = r % 20;
            if      (c < 16)  v = W1[(L*HH + o)*HH + c];
            else if (c == 16) v = b1[L*HH + o];
            else if (c == 17) v = W1[(L*HH + o)*HH + 32];
            else              v = 0.0f;
        } else if (r < PK_WT) {             // wb[o][16] = W1[o][16..31]
            const int q = r - PK_WB, o = q / 16, c = q % 16;
            v = W1[(L*HH + o)*HH + 16 + c];
        } else {                            // wt[o][16] = W2[d][o] transposed
            const int q = r - PK_WT, o = q / 16, d = q % 16;
            v = W2[(L*DD + d)*HH + o];
        }
        wp[i] = v;
    }

    for (int j = tid; j < M_ATM; j += stride) {
        const double y0 = (double)y[j*3+0];
        const double y1 = (double)y[j*3+1];
        const double y2 = (double)y[j*3+2];
        yd[j*4+0] = -2.0*y0;
        yd[j*4+1] = -2.0*y1;
        yd[j*4+2] = -2.0*y2;
        yd[j*4+3] = y0*y0 + y1*y1 + y2*y2;
    }

    for (int j = tid; j < M_ATM; j += stride) {
        const int bcur  = yb[j];
        const int bprev = (j == 0) ? -1 : yb[j-1];
        for (int t = bprev+1; t <= bcur; ++t) seg[t] = j;
        if (j == M_ATM-1) { for (int t = bcur+1; t <= BB; ++t) seg[t] = M_ATM; }
    }
}

// ---------------- KNN: one WAVE per point, packed-u64 selection ----------------
// key = (f64 bits of d^2 with low 12 bits replaced by candidate offset).
// d^2 = sx + |y|^2 - 2 x.y  in f64 (error ~1e-10 << inter-candidate gaps).
__global__ __launch_bounds__(256) void knn_kernel(
    const float* __restrict__ x, const int* __restrict__ xb,
    const double* __restrict__ yd, const int* __restrict__ seg,
    int* __restrict__ out_idx, float* __restrict__ out_d2)
{
    const int wv   = threadIdx.x >> 6;
    const int lane = threadIdx.x & 63;
    const int n    = blockIdx.x * 4 + wv;

    const double x0 = (double)x[n*3+0], x1 = (double)x[n*3+1], x2 = (double)x[n*3+2];
    const double sx = fma(x0, x0, fma(x1, x1, x2*x2));
    const int b  = xb[n];
    const int lo = seg[b];
    const int hi = seg[b+1];
    const double4* __restrict__ ydp = reinterpret_cast<const double4*>(yd);

    // per-lane sorted top-4 packed keys (ascending); ALL1 = +inf sentinel
    unsigned long long m0 = ALL1, m1 = ALL1, m2 = ALL1, m3 = ALL1;
    #pragma unroll
    for (int s = 0; s < SLOTS; ++s) {
        const int j = lo + lane + 64*s;
        if (j < hi) {
            const double4 q = ydp[j];
            double dd = fma(x2, q.z, fma(x1, q.y, fma(x0, q.x, sx + q.w)));
            dd = fmax(dd, 0.0);
            const unsigned long long kb =
                ((unsigned long long)__double_as_longlong(dd) & ~0xFFFull)
                | (unsigned long long)(lane + 64*s);
            if (kb < m3) {
                if      (kb < m0) { m3 = m2; m2 = m1; m1 = m0; m0 = kb; }
                else if (kb < m1) { m3 = m2; m2 = m1; m1 = kb; }
                else if (kb < m2) { m3 = m2; m2 = kb; }
                else              { m3 = kb; }
            }
        }
    }

    unsigned long long cmask = 0ull;   // consumed slots (for rare rebuild)
    unsigned long long res_key = 0ull;

    #define SWZ_MIN(OFF) {                                                    \
        const unsigned int l32 = (unsigned int)bv;                            \
        const unsigned int h32 = (unsigned int)(bv >> 32);                    \
        const unsigned int ol = (unsigned int)__builtin_amdgcn_ds_swizzle((int)l32, OFF); \
        const unsigned int oh = (unsigned int)__builtin_amdgcn_ds_swizzle((int)h32, OFF); \
        const unsigned long long ov = ((unsigned long long)oh << 32) | ol;    \
        bv = (ov < bv) ? ov : bv; }

    for (int r = 0; r < KK; ++r) {
        unsigned long long bv = m0;
        SWZ_MIN(0x041F)   // xor 1
        SWZ_MIN(0x081F)   // xor 2
        SWZ_MIN(0x101F)   // xor 4
        SWZ_MIN(0x201F)   // xor 8
        SWZ_MIN(0x401F)   // xor 16
        {                 // xor 32 (cross-half)
            const unsigned long long ov = __shfl_xor(bv, 32);
            bv = (ov < bv) ? ov : bv;
        }
        const unsigned long long win = bv;   // wave-uniform

        res_key = (lane == r) ? win : res_key;

        const int woff = (int)(win & 0xFFFull);
        if (lane == (woff & 63)) {               // winner lane pops its head
            cmask |= 1ull << (woff >> 6);
            m0 = m1; m1 = m2; m2 = m3; m3 = ALL1;
            if (m0 == ALL1) {
                // rare rebuild (a lane won 4+ times): rescan excluding consumed
                #pragma unroll 1
                for (int s = 0; s < SLOTS; ++s) {
                    const int j = lo + lane + 64*s;
                    if (j < hi && !((cmask >> s) & 1ull)) {
                        const double4 q = ydp[j];
                        double dd = fma(x2, q.z, fma(x1, q.y, fma(x0, q.x, sx + q.w)));
                        dd = fmax(dd, 0.0);
                        const unsigned long long kb =
                            ((unsigned long long)__double_as_longlong(dd) & ~0xFFFull)
                            | (unsigned long long)(lane + 64*s);
                        if (kb < m3) {
                            if      (kb < m0) { m3 = m2; m2 = m1; m1 = m0; m0 = kb; }
                            else if (kb < m1) { m3 = m2; m2 = m1; m1 = kb; }
                            else if (kb < m2) { m3 = m2; m2 = kb; }
                            else              { m3 = kb; }
                        }
                    }
                }
            }
        }
    }
    #undef SWZ_MIN

    if (lane < KK) {
        out_idx[n*KK + lane] = lo + (int)(res_key & 0xFFFull);
        out_d2 [n*KK + lane] =
            (float)__longlong_as_double((long long)(res_key & ~0xFFFull));
    }
}

// ---------------- MP: 8 lanes/point, 2 k's/lane, o-loop unroll 2 ----------------
#define DOT16(res, A, q0, q1, q2, q3)                                   \
    res = fmaf(A[0],  q0.x, res); res = fmaf(A[1],  q0.y, res);         \
    res = fmaf(A[2],  q0.z, res); res = fmaf(A[3],  q0.w, res);         \
    res = fmaf(A[4],  q1.x, res); res = fmaf(A[5],  q1.y, res);         \
    res = fmaf(A[6],  q1.z, res); res = fmaf(A[7],  q1.w, res);         \
    res = fmaf(A[8],  q2.x, res); res = fmaf(A[9],  q2.y, res);         \
    res = fmaf(A[10], q2.z, res); res = fmaf(A[11], q2.w, res);         \
    res = fmaf(A[12], q3.x, res); res = fmaf(A[13], q3.y, res);         \
    res = fmaf(A[14], q3.z, res); res = fmaf(A[15], q3.w, res);

__global__ __launch_bounds__(256) void mp_kernel(
    const int*   __restrict__ nidx, const float* __restrict__ nd2,
    const float* __restrict__ yat,  const float* __restrict__ wpack,
    const float* __restrict__ b2,
    const float* __restrict__ gnw, const float* __restrict__ gnb,
    float* __restrict__ out)
{
    const int g  = blockIdx.x * 256 + threadIdx.x;
    const int n  = g >> 3;
    const int kl = g & 7;

    const int2   iv = *reinterpret_cast<const int2*>  (nidx + n*KK + kl*2);
    const float2 dv = *reinterpret_cast<const float2*>(nd2  + n*KK + kl*2);

    float at0[DD], at1[DD];
    {
        const float4* p0 = reinterpret_cast<const float4*>(yat + (long)iv.x*DD);
        const float4* p1 = reinterpret_cast<const float4*>(yat + (long)iv.y*DD);
        const float4 a = p0[0], b = p0[1], c = p0[2], d = p0[3];
        const float4 e = p1[0], f = p1[1], h = p1[2], i = p1[3];
        at0[0]=a.x; at0[1]=a.y; at0[2]=a.z; at0[3]=a.w;
        at0[4]=b.x; at0[5]=b.y; at0[6]=b.z; at0[7]=b.w;
        at0[8]=c.x; at0[9]=c.y; at0[10]=c.z; at0[11]=c.w;
        at0[12]=d.x; at0[13]=d.y; at0[14]=d.z; at0[15]=d.w;
        at1[0]=e.x; at1[1]=e.y; at1[2]=e.z; at1[3]=e.w;
        at1[4]=f.x; at1[5]=f.y; at1[6]=f.z; at1[7]=f.w;
        at1[8]=h.x; at1[9]=h.y; at1[10]=h.z; at1[11]=h.w;
        at1[12]=i.x; at1[13]=i.y; at1[14]=i.z; at1[15]=i.w;
    }

    float pe[DD];
    #pragma unroll
    for (int h = 0; h < DD; ++h) pe[h] = 1.0f;

    for (int L = 0; L < 3; ++L) {
        const float* wp = wpack + L*PK_LAY;

        float msg[DD];
        {
            const float4* bq = reinterpret_cast<const float4*>(b2 + L*DD);
            const float4 q0 = bq[0], q1 = bq[1], q2 = bq[2], q3 = bq[3];
            msg[0]=2.f*q0.x; msg[1]=2.f*q0.y; msg[2]=2.f*q0.z; msg[3]=2.f*q0.w;
            msg[4]=2.f*q1.x; msg[5]=2.f*q1.y; msg[6]=2.f*q1.z; msg[7]=2.f*q1.w;
            msg[8]=2.f*q2.x; msg[9]=2.f*q2.y; msg[10]=2.f*q2.z; msg[11]=2.f*q2.w;
            msg[12]=2.f*q3.x; msg[13]=2.f*q3.y; msg[14]=2.f*q3.z; msg[15]=2.f*q3.w;
        }

        #pragma unroll 2
        for (int o = 0; o < HH; ++o) {
            const float4* wx = reinterpret_cast<const float4*>(wp + PK_WX + o*20);
            const float4 x0 = wx[0], x1 = wx[1], x2 = wx[2], x3 = wx[3], x4 = wx[4];
            const float4* wb = reinterpret_cast<const float4*>(wp + PK_WB + o*16);
            const float4 y0 = wb[0], y1 = wb[1], y2 = wb[2], y3 = wb[3];
            const float4* wt = reinterpret_cast<const float4*>(wp + PK_WT + o*16);
            const float4 t0 = wt[0], t1 = wt[1], t2 = wt[2], t3 = wt[3];

            float bas = x4.x;                 // b1[o]
            DOT16(bas, pe, x0, x1, x2, x3);   // + pe . W1a[o]

            float u0 = fmaf(dv.x, x4.y, bas); // + dist*W1[o][32]
            DOT16(u0, at0, y0, y1, y2, y3);
            float u1 = fmaf(dv.y, x4.y, bas);
            DOT16(u1, at1, y0, y1, y2, y3);

            const float hs = fmaxf(u0, SLOPE*u0) + fmaxf(u1, SLOPE*u1);

            msg[0]  = fmaf(hs, t0.x, msg[0]);  msg[1]  = fmaf(hs, t0.y, msg[1]);
            msg[2]  = fmaf(hs, t0.z, msg[2]);  msg[3]  = fmaf(hs, t0.w, msg[3]);
            msg[4]  = fmaf(hs, t1.x, msg[4]);  msg[5]  = fmaf(hs, t1.y, msg[5]);
            msg[6]  = fmaf(hs, t1.z, msg[6]);  msg[7]  = fmaf(hs, t1.w, msg[7]);
            msg[8]  = fmaf(hs, t2.x, msg[8]);  msg[9]  = fmaf(hs, t2.y, msg[9]);
            msg[10] = fmaf(hs, t2.z, msg[10]); msg[11] = fmaf(hs, t2.w, msg[11]);
            msg[12] = fmaf(hs, t3.x, msg[12]); msg[13] = fmaf(hs, t3.y, msg[13]);
            msg[14] = fmaf(hs, t3.z, msg[14]); msg[15] = fmaf(hs, t3.w, msg[15]);
        }

        // sum partial msg over the 8 lanes of this point
        #pragma unroll
        for (int o = 0; o < DD; ++o) {
            msg[o] += __shfl_xor(msg[o], 1);
            msg[o] += __shfl_xor(msg[o], 2);
            msg[o] += __shfl_xor(msg[o], 4);
        }

        // GroupNorm(2,16) + leaky + residual (redundant per lane)
        const float4* gw = reinterpret_cast<const float4*>(gnw + L*DD);
        const float4* gb = reinterpret_cast<const float4*>(gnb + L*DD);
        const float4 gw0 = gw[0], gw1 = gw[1], gw2 = gw[2], gw3 = gw[3];
        const float4 gb0 = gb[0], gb1 = gb[1], gb2 = gb[2], gb3 = gb[3];
        const float gwa[DD] = { gw0.x,gw0.y,gw0.z,gw0.w, gw1.x,gw1.y,gw1.z,gw1.w,
                                gw2.x,gw2.y,gw2.z,gw2.w, gw3.x,gw3.y,gw3.z,gw3.w };
        const float gba[DD] = { gb0.x,gb0.y,gb0.z,gb0.w, gb1.x,gb1.y,gb1.z,gb1.w,
                                gb2.x,gb2.y,gb2.z,gb2.w, gb3.x,gb3.y,gb3.z,gb3.w };
        #pragma unroll
        for (int grp = 0; grp < 2; ++grp) {
            float mu = 0.0f;
            #pragma unroll
            for (int j = 0; j < 8; ++j) mu += msg[grp*8 + j];
            mu *= 0.125f;
            float var = 0.0f;
            #pragma unroll
            for (int j = 0; j < 8; ++j) { const float d = msg[grp*8 + j] - mu; var = fmaf(d, d, var); }
            var *= 0.125f;
            const float rs = rsqrtf(var + EPSGN);
            #pragma unroll
            for (int j = 0; j < 8; ++j) {
                const int c = grp*8 + j;
                const float v = (msg[c] - mu) * rs * gwa[c] + gba[c];
                pe[c] += fmaxf(v, SLOPE * v);
            }
        }
    }

    if (kl == 0) {
        float4* op = reinterpret_cast<float4*>(out + (long)n*DD);
        op[0] = make_float4(pe[0],  pe[1],  pe[2],  pe[3]);
        op[1] = make_float4(pe[4],  pe[5],  pe[6],  pe[7]);
        op[2] = make_float4(pe[8],  pe[9],  pe[10], pe[11]);
        op[3] = make_float4(pe[12], pe[13], pe[14], pe[15]);
    }
}

extern "C" void kernel_launch(void* const* d_in, const int* in_sizes, int n_in,
                              void* d_out, int out_size, void* d_ws, size_t ws_size,
                              hipStream_t stream) {
    const float* x   = (const float*)d_in[0];
    const float* y   = (const float*)d_in[1];
    const float* yat = (const float*)d_in[2];
    const int*   xb  = (const int*)  d_in[3];
    const int*   yb  = (const int*)  d_in[4];
    const float* W1  = (const float*)d_in[5];
    const float* b1  = (const float*)d_in[6];
    const float* W2  = (const float*)d_in[7];
    const float* b2  = (const float*)d_in[8];
    const float* gnw = (const float*)d_in[9];
    const float* gnb = (const float*)d_in[10];
    float* out = (float*)d_out;

    double* yd     = (double*)((char*)d_ws + WS_YD);
    int*    seg    = (int*)   ((char*)d_ws + WS_SEG);
    float*  wpack  = (float*) ((char*)d_ws + WS_WP);
    int*    ws_idx = (int*)   ((char*)d_ws + WS_IDX);
    float*  ws_d2  = (float*) ((char*)d_ws + WS_D2);

    repack_kernel<<<8, 256, 0, stream>>>(W1, b1, W2, y, yb, wpack, yd, seg);
    knn_kernel<<<N_PTS/4, 256, 0, stream>>>(x, xb, yd, seg, ws_idx, ws_d2);
    mp_kernel<<<(N_PTS*8)/256, 256, 0, stream>>>(
        ws_idx, ws_d2, yat, wpack, b2, gnw, gnb, out);
}

// Round 7
// 113.549 us; speedup vs baseline: 1.1782x; 1.1782x over previous
//
#include <hip/hip_runtime.h>
#include <math.h>

#define N_PTS 20000
#define M_ATM 8000
#define DD    16
#define KK    16
#define HH    33
#define BB    4
#define EPSGN 1e-5f
#define SLOPE 0.2f
#define SLOTS 36   // 36*64 = 2304 candidates/wave >= max batch segment
#define ALL1  0xFFFFFFFFFFFFFFFFull

// packed layout per layer (floats): wx[33][20] | wb[33][16] | wt[33][16]
#define PK_WX   0
#define PK_WB   660
#define PK_WT   1188
#define PK_LAY  1716

// ws layout (bytes)
#define WS_YD    0                       // 8000 * 32 B f64 (-2y0,-2y1,-2y2,|y|^2)
#define WS_SEG   256000                  // 5 ints (+pad)
#define WS_WP    256064                  // 3*1716 floats
#define WS_IDX   276672                  // N*K ints
#define WS_D2    (276672 + 1280000)      // N*K floats

// ---------------- repack: weights + f64 atom table + batch boundaries ----------------
__global__ void repack_kernel(const float* __restrict__ W1, const float* __restrict__ b1,
                              const float* __restrict__ W2,
                              const float* __restrict__ y, const int* __restrict__ yb,
                              float* __restrict__ wp, double* __restrict__ yd,
                              int* __restrict__ seg)
{
    const int tid = blockIdx.x*256 + threadIdx.x;
    const int stride = gridDim.x*256;

    for (int i = tid; i < 3*PK_LAY; i += stride) {
        const int L = i / PK_LAY, r = i % PK_LAY;
        float v;
        if (r < PK_WB) {                    // wx[o][20] = W1a(16) | b1 | w_dist | pad2
            const int o = r / 20, c = r % 20;
            if      (c < 16)  v = W1[(L*HH + o)*HH + c];
            else if (c == 16) v = b1[L*HH + o];
            else if (c == 17) v = W1[(L*HH + o)*HH + 32];
            else              v = 0.0f;
        } else if (r < PK_WT) {             // wb[o][16] = W1[o][16..31]
            const int q = r - PK_WB, o = q / 16, c = q % 16;
            v = W1[(L*HH + o)*HH + 16 + c];
        } else {                            // wt[o][16] = W2[d][o] transposed
            const int q = r - PK_WT, o = q / 16, d = q % 16;
            v = W2[(L*DD + d)*HH + o];
        }
        wp[i] = v;
    }

    for (int j = tid; j < M_ATM; j += stride) {
        const double y0 = (double)y[j*3+0];
        const double y1 = (double)y[j*3+1];
        const double y2 = (double)y[j*3+2];
        yd[j*4+0] = -2.0*y0;
        yd[j*4+1] = -2.0*y1;
        yd[j*4+2] = -2.0*y2;
        yd[j*4+3] = y0*y0 + y1*y1 + y2*y2;
    }

    for (int j = tid; j < M_ATM; j += stride) {
        const int bcur  = yb[j];
        const int bprev = (j == 0) ? -1 : yb[j-1];
        for (int t = bprev+1; t <= bcur; ++t) seg[t] = j;
        if (j == M_ATM-1) { for (int t = bcur+1; t <= BB; ++t) seg[t] = M_ATM; }
    }
}

// ---------------- KNN: one WAVE per point, packed-u64 selection ----------------
// key = (f64 bits of d^2 with low 12 bits replaced by candidate offset).
// Round-min: butterfly on HIGH 32 bits only (1 swizzle + 1 v_min_u32 per stage);
// unique winner extracted via ballot + readlane; exact u64 fallback on hi-ties.
__global__ __launch_bounds__(256) void knn_kernel(
    const float* __restrict__ x, const int* __restrict__ xb,
    const double* __restrict__ yd, const int* __restrict__ seg,
    int* __restrict__ out_idx, float* __restrict__ out_d2)
{
    const int wv   = threadIdx.x >> 6;
    const int lane = threadIdx.x & 63;
    const int n    = blockIdx.x * 4 + wv;

    const double x0 = (double)x[n*3+0], x1 = (double)x[n*3+1], x2 = (double)x[n*3+2];
    const double sx = fma(x0, x0, fma(x1, x1, x2*x2));
    const int b  = xb[n];
    const int lo = seg[b];
    const int hi = seg[b+1];
    const double4* __restrict__ ydp = reinterpret_cast<const double4*>(yd);

    // per-lane sorted top-4 packed keys (ascending); ALL1 = +inf sentinel
    unsigned long long m0 = ALL1, m1 = ALL1, m2 = ALL1, m3 = ALL1;
    #pragma unroll
    for (int s = 0; s < SLOTS; ++s) {
        const int j = lo + lane + 64*s;
        if (j < hi) {
            const double4 q = ydp[j];
            double dd = fma(x2, q.z, fma(x1, q.y, fma(x0, q.x, sx + q.w)));
            dd = fmax(dd, 0.0);
            const unsigned long long kb =
                ((unsigned long long)__double_as_longlong(dd) & ~0xFFFull)
                | (unsigned long long)(lane + 64*s);
            if (kb < m3) {
                if      (kb < m0) { m3 = m2; m2 = m1; m1 = m0; m0 = kb; }
                else if (kb < m1) { m3 = m2; m2 = m1; m1 = kb; }
                else if (kb < m2) { m3 = m2; m2 = kb; }
                else              { m3 = kb; }
            }
        }
    }

    unsigned long long cmask = 0ull;   // consumed slots (for rare rebuild)
    unsigned long long res_key = 0ull;

    #define SWZ_MIN64(OFF) {                                                  \
        const unsigned int l32 = (unsigned int)bv;                            \
        const unsigned int h32 = (unsigned int)(bv >> 32);                    \
        const unsigned int ol = (unsigned int)__builtin_amdgcn_ds_swizzle((int)l32, OFF); \
        const unsigned int oh = (unsigned int)__builtin_amdgcn_ds_swizzle((int)h32, OFF); \
        const unsigned long long ov = ((unsigned long long)oh << 32) | ol;    \
        bv = (ov < bv) ? ov : bv; }

    #define SWZ_MIN32(OFF) {                                                  \
        const unsigned int o32 = (unsigned int)__builtin_amdgcn_ds_swizzle((int)h, OFF); \
        h = (o32 < h) ? o32 : h; }

    for (int r = 0; r < KK; ++r) {
        // 1) wave-min of key HIGH words (cheap 32-bit butterfly)
        const unsigned int bh = (unsigned int)(m0 >> 32);
        unsigned int h = bh;
        SWZ_MIN32(0x041F)   // xor 1
        SWZ_MIN32(0x081F)   // xor 2
        SWZ_MIN32(0x101F)   // xor 4
        SWZ_MIN32(0x201F)   // xor 8
        SWZ_MIN32(0x401F)   // xor 16
        {                   // xor 32 (cross-half)
            const unsigned int o32 = (unsigned int)__shfl_xor((int)h, 32);
            h = (o32 < h) ? o32 : h;
        }

        // 2) unique winner fast path; exact u64 fallback on high-word ties
        const unsigned long long tied = __ballot(bh == h);
        unsigned long long win;
        if (__popcll(tied) == 1) {
            const int w = __builtin_ctzll(tied);           // wave-uniform
            const unsigned int wl = (unsigned int)
                __builtin_amdgcn_readlane((int)(unsigned int)m0, w);
            win = ((unsigned long long)h << 32) | wl;
        } else {
            unsigned long long bv = m0;
            SWZ_MIN64(0x041F)
            SWZ_MIN64(0x081F)
            SWZ_MIN64(0x101F)
            SWZ_MIN64(0x201F)
            SWZ_MIN64(0x401F)
            const unsigned long long ov = __shfl_xor(bv, 32);
            bv = (ov < bv) ? ov : bv;
            win = bv;
        }

        res_key = (lane == r) ? win : res_key;

        const int woff = (int)(win & 0xFFFull);
        if (lane == (woff & 63)) {               // winner lane pops its head
            cmask |= 1ull << (woff >> 6);
            m0 = m1; m1 = m2; m2 = m3; m3 = ALL1;
            if (m0 == ALL1) {
                // rare rebuild (a lane won 4+ times): rescan excluding consumed
                #pragma unroll 1
                for (int s = 0; s < SLOTS; ++s) {
                    const int j = lo + lane + 64*s;
                    if (j < hi && !((cmask >> s) & 1ull)) {
                        const double4 q = ydp[j];
                        double dd = fma(x2, q.z, fma(x1, q.y, fma(x0, q.x, sx + q.w)));
                        dd = fmax(dd, 0.0);
                        const unsigned long long kb =
                            ((unsigned long long)__double_as_longlong(dd) & ~0xFFFull)
                            | (unsigned long long)(lane + 64*s);
                        if (kb < m3) {
                            if      (kb < m0) { m3 = m2; m2 = m1; m1 = m0; m0 = kb; }
                            else if (kb < m1) { m3 = m2; m2 = m1; m1 = kb; }
                            else if (kb < m2) { m3 = m2; m2 = kb; }
                            else              { m3 = kb; }
                        }
                    }
                }
            }
        }
    }
    #undef SWZ_MIN64
    #undef SWZ_MIN32

    if (lane < KK) {
        out_idx[n*KK + lane] = lo + (int)(res_key & 0xFFFull);
        out_d2 [n*KK + lane] =
            (float)__longlong_as_double((long long)(res_key & ~0xFFFull));
    }
}

// ---------------- MP: 8 lanes/point, 2 k's/lane, rolled o-loop ----------------
#define DOT16(res, A, q0, q1, q2, q3)                                   \
    res = fmaf(A[0],  q0.x, res); res = fmaf(A[1],  q0.y, res);         \
    res = fmaf(A[2],  q0.z, res); res = fmaf(A[3],  q0.w, res);         \
    res = fmaf(A[4],  q1.x, res); res = fmaf(A[5],  q1.y, res);         \
    res = fmaf(A[6],  q1.z, res); res = fmaf(A[7],  q1.w, res);         \
    res = fmaf(A[8],  q2.x, res); res = fmaf(A[9],  q2.y, res);         \
    res = fmaf(A[10], q2.z, res); res = fmaf(A[11], q2.w, res);         \
    res = fmaf(A[12], q3.x, res); res = fmaf(A[13], q3.y, res);         \
    res = fmaf(A[14], q3.z, res); res = fmaf(A[15], q3.w, res);

__global__ __launch_bounds__(256) void mp_kernel(
    const int*   __restrict__ nidx, const float* __restrict__ nd2,
    const float* __restrict__ yat,  const float* __restrict__ wpack,
    const float* __restrict__ b2,
    const float* __restrict__ gnw, const float* __restrict__ gnb,
    float* __restrict__ out)
{
    const int g  = blockIdx.x * 256 + threadIdx.x;
    const int n  = g >> 3;
    const int kl = g & 7;

    const int2   iv = *reinterpret_cast<const int2*>  (nidx + n*KK + kl*2);
    const float2 dv = *reinterpret_cast<const float2*>(nd2  + n*KK + kl*2);

    float at0[DD], at1[DD];
    {
        const float4* p0 = reinterpret_cast<const float4*>(yat + (long)iv.x*DD);
        const float4* p1 = reinterpret_cast<const float4*>(yat + (long)iv.y*DD);
        const float4 a = p0[0], b = p0[1], c = p0[2], d = p0[3];
        const float4 e = p1[0], f = p1[1], h = p1[2], i = p1[3];
        at0[0]=a.x; at0[1]=a.y; at0[2]=a.z; at0[3]=a.w;
        at0[4]=b.x; at0[5]=b.y; at0[6]=b.z; at0[7]=b.w;
        at0[8]=c.x; at0[9]=c.y; at0[10]=c.z; at0[11]=c.w;
        at0[12]=d.x; at0[13]=d.y; at0[14]=d.z; at0[15]=d.w;
        at1[0]=e.x; at1[1]=e.y; at1[2]=e.z; at1[3]=e.w;
        at1[4]=f.x; at1[5]=f.y; at1[6]=f.z; at1[7]=f.w;
        at1[8]=h.x; at1[9]=h.y; at1[10]=h.z; at1[11]=h.w;
        at1[12]=i.x; at1[13]=i.y; at1[14]=i.z; at1[15]=i.w;
    }

    float pe[DD];
    #pragma unroll
    for (int h = 0; h < DD; ++h) pe[h] = 1.0f;

    for (int L = 0; L < 3; ++L) {
        const float* wp = wpack + L*PK_LAY;

        float msg[DD];
        {
            const float4* bq = reinterpret_cast<const float4*>(b2 + L*DD);
            const float4 q0 = bq[0], q1 = bq[1], q2 = bq[2], q3 = bq[3];
            msg[0]=2.f*q0.x; msg[1]=2.f*q0.y; msg[2]=2.f*q0.z; msg[3]=2.f*q0.w;
            msg[4]=2.f*q1.x; msg[5]=2.f*q1.y; msg[6]=2.f*q1.z; msg[7]=2.f*q1.w;
            msg[8]=2.f*q2.x; msg[9]=2.f*q2.y; msg[10]=2.f*q2.z; msg[11]=2.f*q2.w;
            msg[12]=2.f*q3.x; msg[13]=2.f*q3.y; msg[14]=2.f*q3.z; msg[15]=2.f*q3.w;
        }

        #pragma unroll 1
        for (int o = 0; o < HH; ++o) {
            const float4* wx = reinterpret_cast<const float4*>(wp + PK_WX + o*20);
            const float4 x0 = wx[0], x1 = wx[1], x2 = wx[2], x3 = wx[3], x4 = wx[4];
            const float4* wb = reinterpret_cast<const float4*>(wp + PK_WB + o*16);
            const float4 y0 = wb[0], y1 = wb[1], y2 = wb[2], y3 = wb[3];
            const float4* wt = reinterpret_cast<const float4*>(wp + PK_WT + o*16);
            const float4 t0 = wt[0], t1 = wt[1], t2 = wt[2], t3 = wt[3];

            float bas = x4.x;                 // b1[o]
            DOT16(bas, pe, x0, x1, x2, x3);   // + pe . W1a[o]

            float u0 = fmaf(dv.x, x4.y, bas); // + dist*W1[o][32]
            DOT16(u0, at0, y0, y1, y2, y3);
            float u1 = fmaf(dv.y, x4.y, bas);
            DOT16(u1, at1, y0, y1, y2, y3);

            const float hs = fmaxf(u0, SLOPE*u0) + fmaxf(u1, SLOPE*u1);

            msg[0]  = fmaf(hs, t0.x, msg[0]);  msg[1]  = fmaf(hs, t0.y, msg[1]);
            msg[2]  = fmaf(hs, t0.z, msg[2]);  msg[3]  = fmaf(hs, t0.w, msg[3]);
            msg[4]  = fmaf(hs, t1.x, msg[4]);  msg[5]  = fmaf(hs, t1.y, msg[5]);
            msg[6]  = fmaf(hs, t1.z, msg[6]);  msg[7]  = fmaf(hs, t1.w, msg[7]);
            msg[8]  = fmaf(hs, t2.x, msg[8]);  msg[9]  = fmaf(hs, t2.y, msg[9]);
            msg[10] = fmaf(hs, t2.z, msg[10]); msg[11] = fmaf(hs, t2.w, msg[11]);
            msg[12] = fmaf(hs, t3.x, msg[12]); msg[13] = fmaf(hs, t3.y, msg[13]);
            msg[14] = fmaf(hs, t3.z, msg[14]); msg[15] = fmaf(hs, t3.w, msg[15]);
        }

        // sum partial msg over the 8 lanes of this point
        #pragma unroll
        for (int o = 0; o < DD; ++o) {
            msg[o] += __shfl_xor(msg[o], 1);
            msg[o] += __shfl_xor(msg[o], 2);
            msg[o] += __shfl_xor(msg[o], 4);
        }

        // GroupNorm(2,16) + leaky + residual (redundant per lane)
        const float4* gw = reinterpret_cast<const float4*>(gnw + L*DD);
        const float4* gb = reinterpret_cast<const float4*>(gnb + L*DD);
        const float4 gw0 = gw[0], gw1 = gw[1], gw2 = gw[2], gw3 = gw[3];
        const float4 gb0 = gb[0], gb1 = gb[1], gb2 = gb[2], gb3 = gb[3];
        const float gwa[DD] = { gw0.x,gw0.y,gw0.z,gw0.w, gw1.x,gw1.y,gw1.z,gw1.w,
                                gw2.x,gw2.y,gw2.z,gw2.w, gw3.x,gw3.y,gw3.z,gw3.w };
        const float gba[DD] = { gb0.x,gb0.y,gb0.z,gb0.w, gb1.x,gb1.y,gb1.z,gb1.w,
                                gb2.x,gb2.y,gb2.z,gb2.w, gb3.x,gb3.y,gb3.z,gb3.w };
        #pragma unroll
        for (int grp = 0; grp < 2; ++grp) {
            float mu = 0.0f;
            #pragma unroll
            for (int j = 0; j < 8; ++j) mu += msg[grp*8 + j];
            mu *= 0.125f;
            float var = 0.0f;
            #pragma unroll
            for (int j = 0; j < 8; ++j) { const float d = msg[grp*8 + j] - mu; var = fmaf(d, d, var); }
            var *= 0.125f;
            const float rs = rsqrtf(var + EPSGN);
            #pragma unroll
            for (int j = 0; j < 8; ++j) {
                const int c = grp*8 + j;
                const float v = (msg[c] - mu) * rs * gwa[c] + gba[c];
                pe[c] += fmaxf(v, SLOPE * v);
            }
        }
    }

    if (kl == 0) {
        float4* op = reinterpret_cast<float4*>(out + (long)n*DD);
        op[0] = make_float4(pe[0],  pe[1],  pe[2],  pe[3]);
        op[1] = make_float4(pe[4],  pe[5],  pe[6],  pe[7]);
        op[2] = make_float4(pe[8],  pe[9],  pe[10], pe[11]);
        op[3] = make_float4(pe[12], pe[13], pe[14], pe[15]);
    }
}

extern "C" void kernel_launch(void* const* d_in, const int* in_sizes, int n_in,
                              void* d_out, int out_size, void* d_ws, size_t ws_size,
                              hipStream_t stream) {
    const float* x   = (const float*)d_in[0];
    const float* y   = (const float*)d_in[1];
    const float* yat = (const float*)d_in[2];
    const int*   xb  = (const int*)  d_in[3];
    const int*   yb  = (const int*)  d_in[4];
    const float* W1  = (const float*)d_in[5];
    const float* b1  = (const float*)d_in[6];
    const float* W2  = (const float*)d_in[7];
    const float* b2  = (const float*)d_in[8];
    const float* gnw = (const float*)d_in[9];
    const float* gnb = (const float*)d_in[10];
    float* out = (float*)d_out;

    double* yd     = (double*)((char*)d_ws + WS_YD);
    int*    seg    = (int*)   ((char*)d_ws + WS_SEG);
    float*  wpack  = (float*) ((char*)d_ws + WS_WP);
    int*    ws_idx = (int*)   ((char*)d_ws + WS_IDX);
    float*  ws_d2  = (float*) ((char*)d_ws + WS_D2);

    repack_kernel<<<16, 256, 0, stream>>>(W1, b1, W2, y, yb, wpack, yd, seg);
    knn_kernel<<<N_PTS/4, 256, 0, stream>>>(x, xb, yd, seg, ws_idx, ws_d2);
    mp_kernel<<<(N_PTS*8)/256, 256, 0, stream>>>(
        ws_idx, ws_d2, yat, wpack, b2, gnw, gnb, out);
}

// Round 8
// 103.520 us; speedup vs baseline: 1.2924x; 1.0969x over previous
//
#include <hip/hip_runtime.h>
#include <math.h>

#define N_PTS 20000
#define M_ATM 8000
#define DD    16
#define KK    16
#define HH    33
#define BB    4
#define EPSGN 1e-5f
#define SLOPE 0.2f
#define SLOTS 36   // 36*64 = 2304 candidates/wave >= max batch segment
#define ALL1  0xFFFFFFFFFFFFFFFFull
#define FMARG 5e-3f   // f32-vs-f64 pairwise ordering error margin (bound ~2e-3)

// packed layout per layer (floats): wx[33][20] | wb[33][16] | wt[33][16]
#define PK_WX   0
#define PK_WB   660
#define PK_WT   1188
#define PK_LAY  1716

// ws layout (bytes)
#define WS_YF    0                       // 8000 * 16 B f32 (-2y0,-2y1,-2y2,|y|^2)
#define WS_SEG   128000                  // 5 ints (+pad)
#define WS_WP    128064                  // 3*1716 floats -> ends 148656
#define WS_IDX   148672                  // N*K ints
#define WS_D2    (148672 + 1280000)      // N*K floats

// ---------------- repack: weights + f32 atom table + batch boundaries ----------------
__global__ void repack_kernel(const float* __restrict__ W1, const float* __restrict__ b1,
                              const float* __restrict__ W2,
                              const float* __restrict__ y, const int* __restrict__ yb,
                              float* __restrict__ wp, float* __restrict__ yf,
                              int* __restrict__ seg)
{
    const int tid = blockIdx.x*256 + threadIdx.x;
    const int stride = gridDim.x*256;

    for (int i = tid; i < 3*PK_LAY; i += stride) {
        const int L = i / PK_LAY, r = i % PK_LAY;
        float v;
        if (r < PK_WB) {                    // wx[o][20] = W1a(16) | b1 | w_dist | pad2
            const int o = r / 20, c = r % 20;
            if      (c < 16)  v = W1[(L*HH + o)*HH + c];
            else if (c == 16) v = b1[L*HH + o];
            else if (c == 17) v = W1[(L*HH + o)*HH + 32];
            else              v = 0.0f;
        } else if (r < PK_WT) {             // wb[o][16] = W1[o][16..31]
            const int q = r - PK_WB, o = q / 16, c = q % 16;
            v = W1[(L*HH + o)*HH + 16 + c];
        } else {                            // wt[o][16] = W2[d][o] transposed
            const int q = r - PK_WT, o = q / 16, d = q % 16;
            v = W2[(L*DD + d)*HH + o];
        }
        wp[i] = v;
    }

    for (int j = tid; j < M_ATM; j += stride) {
        const double y0 = (double)y[j*3+0];
        const double y1 = (double)y[j*3+1];
        const double y2 = (double)y[j*3+2];
        yf[j*4+0] = (float)(-2.0*y0);
        yf[j*4+1] = (float)(-2.0*y1);
        yf[j*4+2] = (float)(-2.0*y2);
        yf[j*4+3] = (float)(y0*y0 + y1*y1 + y2*y2);
    }

    for (int j = tid; j < M_ATM; j += stride) {
        const int bcur  = yb[j];
        const int bprev = (j == 0) ? -1 : yb[j-1];
        for (int t = bprev+1; t <= bcur; ++t) seg[t] = j;
        if (j == M_ATM-1) { for (int t = bcur+1; t <= BB; ++t) seg[t] = M_ATM; }
    }
}

__device__ __forceinline__ unsigned wave_min_u32(unsigned v) {
    #define SW(OFF) { const unsigned o = (unsigned)__builtin_amdgcn_ds_swizzle((int)v, OFF); v = (o < v) ? o : v; }
    SW(0x041F) SW(0x081F) SW(0x101F) SW(0x201F) SW(0x401F)
    #undef SW
    { const unsigned o = (unsigned)__shfl_xor((int)v, 32); v = (o < v) ? o : v; }
    return v;
}

// ---------------- KNN: one WAVE per point, f32 select + f64 boundary finalize ----
// key = ((u64)f32bits(d2) << 32) | offset.  Top-16 set by f32 + FMARG margin,
// exact f64 rank-select among the <=24 survivors (set semantics: output order
// is irrelevant because mp sums over k).
__global__ __launch_bounds__(256) void knn_kernel(
    const float* __restrict__ x, const int* __restrict__ xb,
    const float* __restrict__ yf, const int* __restrict__ seg,
    const float* __restrict__ yg,
    int* __restrict__ out_idx, float* __restrict__ out_d2)
{
    const int wv   = threadIdx.x >> 6;
    const int lane = threadIdx.x & 63;
    const int n    = blockIdx.x * 4 + wv;

    const float xf0 = x[n*3+0], xf1 = x[n*3+1], xf2 = x[n*3+2];
    const float sxf = fmaf(xf0, xf0, fmaf(xf1, xf1, xf2*xf2));
    const int b  = xb[n];
    const int lo = seg[b];
    const int hi = seg[b+1];
    const float4* __restrict__ yfp = reinterpret_cast<const float4*>(yf);

    // per-lane sorted top-4 packed keys (ascending); ALL1 = +inf sentinel
    unsigned long long m0 = ALL1, m1 = ALL1, m2 = ALL1, m3 = ALL1;
    #pragma unroll
    for (int s = 0; s < SLOTS; ++s) {
        const int j = lo + lane + 64*s;
        if (j < hi) {
            const float4 q = yfp[j];
            float dd = fmaf(xf2, q.z, fmaf(xf1, q.y, fmaf(xf0, q.x, sxf + q.w)));
            dd = fmaxf(dd, 0.0f);
            const unsigned long long kb =
                ((unsigned long long)__float_as_uint(dd) << 32)
                | (unsigned)(lane + 64*s);
            if (kb < m3) {
                if      (kb < m0) { m3 = m2; m2 = m1; m1 = m0; m0 = kb; }
                else if (kb < m1) { m3 = m2; m2 = m1; m1 = kb; }
                else if (kb < m2) { m3 = m2; m2 = kb; }
                else              { m3 = kb; }
            }
        }
    }

    unsigned long long cmask = 0ull;   // consumed slots (for rare rebuild)
    unsigned res_off = 0;              // this lane's extracted candidate offset
    unsigned h16 = 0;                  // f32 bits of the 16th-smallest

    // pop winner lane w's head; rebuild top-4 from remaining if exhausted
    #define POPWIN(W)                                                         \
        if (lane == (W)) {                                                    \
            cmask |= 1ull << (((unsigned)m0) >> 6);                           \
            m0 = m1; m1 = m2; m2 = m3; m3 = ALL1;                             \
            if (m0 == ALL1) {                                                 \
                _Pragma("unroll 1")                                           \
                for (int s2 = 0; s2 < SLOTS; ++s2) {                          \
                    const int j2 = lo + lane + 64*s2;                         \
                    if (j2 < hi && !((cmask >> s2) & 1ull)) {                 \
                        const float4 q2 = yfp[j2];                            \
                        float d2f = fmaf(xf2, q2.z, fmaf(xf1, q2.y,           \
                                     fmaf(xf0, q2.x, sxf + q2.w)));           \
                        d2f = fmaxf(d2f, 0.0f);                               \
                        const unsigned long long kb2 =                        \
                            ((unsigned long long)__float_as_uint(d2f) << 32)  \
                            | (unsigned)(lane + 64*s2);                       \
                        if (kb2 < m3) {                                       \
                            if      (kb2 < m0) { m3=m2; m2=m1; m1=m0; m0=kb2; }\
                            else if (kb2 < m1) { m3=m2; m2=m1; m1=kb2; }      \
                            else if (kb2 < m2) { m3=m2; m2=kb2; }             \
                            else               { m3=kb2; }                    \
                        }                                                     \
                    }                                                         \
                }                                                             \
            }                                                                 \
        }

    for (int r = 0; r < KK; ++r) {
        const unsigned bh = (unsigned)(m0 >> 32);
        const unsigned h  = wave_min_u32(bh);
        const unsigned long long tied = __ballot(bh == h);
        const int w = (int)__builtin_ctzll(tied);
        const unsigned off = (unsigned)__builtin_amdgcn_readlane((int)(unsigned)m0, w);
        if (lane == r) res_off = off;
        h16 = h;                              // last assignment = round 15
        POPWIN(w)
    }

    // margin extras: keep extracting while next f32 min <= d16 + FMARG
    int e = 0;
    const float flim = __uint_as_float(h16) + FMARG;
    while (e < 8) {
        const unsigned bh = (unsigned)(m0 >> 32);
        const unsigned h  = wave_min_u32(bh);
        if (__uint_as_float(h) > flim) break;
        const unsigned long long tied = __ballot(bh == h);
        const int w = (int)__builtin_ctzll(tied);
        const unsigned off = (unsigned)__builtin_amdgcn_readlane((int)(unsigned)m0, w);
        if (lane == KK + e) res_off = off;
        POPWIN(w)
        ++e;
    }
    #undef POPWIN

    // finalize: exact f64 distances for the 16+e survivors
    const int nact = KK + e;
    const bool have = (lane < nact);
    double dd64 = 0.0;
    if (have) {
        const int j = lo + (int)res_off;
        const double yy0 = (double)yg[j*3+0];
        const double yy1 = (double)yg[j*3+1];
        const double yy2 = (double)yg[j*3+2];
        const double xd0 = (double)xf0, xd1 = (double)xf1, xd2 = (double)xf2;
        const double sxd = fma(xd0, xd0, fma(xd1, xd1, xd2*xd2));
        const double syd = fma(yy0, yy0, fma(yy1, yy1, yy2*yy2));
        dd64 = fma(xd2, -2.0*yy2, fma(xd1, -2.0*yy1, fma(xd0, -2.0*yy0, sxd + syd)));
        dd64 = fmax(dd64, 0.0);
    }

    if (e == 0) {
        if (have) {
            out_idx[n*KK + lane] = lo + (int)res_off;
            out_d2 [n*KK + lane] = (float)dd64;
        }
    } else {
        // exact u64 keys (f64 bits, low 12 -> offset; unique => strict order)
        const unsigned long long fkey = have
            ? (((unsigned long long)__double_as_longlong(dd64) & ~0xFFFull) | res_off)
            : ALL1;
        int rank = 0;
        #pragma unroll 1
        for (int t = 0; t < nact; ++t) {
            const unsigned klo = (unsigned)__builtin_amdgcn_readlane((int)(unsigned)fkey, t);
            const unsigned khi = (unsigned)__builtin_amdgcn_readlane((int)(unsigned)(fkey >> 32), t);
            const unsigned long long kt = ((unsigned long long)khi << 32) | klo;
            rank += (kt < fkey) ? 1 : 0;
        }
        if (have && rank < KK) {
            out_idx[n*KK + rank] = lo + (int)res_off;
            out_d2 [n*KK + rank] = (float)dd64;
        }
    }
}

// ---------------- MP: 8 lanes/point, 2 k's/lane, rolled o-loop, 2-chain dots ----
#define DOT16(res, A, q0, q1, q2, q3) {                                 \
    float _e = res, _o = 0.0f;                                          \
    _e = fmaf(A[0],  q0.x, _e); _o = fmaf(A[1],  q0.y, _o);             \
    _e = fmaf(A[2],  q0.z, _e); _o = fmaf(A[3],  q0.w, _o);             \
    _e = fmaf(A[4],  q1.x, _e); _o = fmaf(A[5],  q1.y, _o);             \
    _e = fmaf(A[6],  q1.z, _e); _o = fmaf(A[7],  q1.w, _o);             \
    _e = fmaf(A[8],  q2.x, _e); _o = fmaf(A[9],  q2.y, _o);             \
    _e = fmaf(A[10], q2.z, _e); _o = fmaf(A[11], q2.w, _o);             \
    _e = fmaf(A[12], q3.x, _e); _o = fmaf(A[13], q3.y, _o);             \
    _e = fmaf(A[14], q3.z, _e); _o = fmaf(A[15], q3.w, _o);             \
    res = _e + _o; }

__global__ __launch_bounds__(256) void mp_kernel(
    const int*   __restrict__ nidx, const float* __restrict__ nd2,
    const float* __restrict__ yat,  const float* __restrict__ wpack,
    const float* __restrict__ b2,
    const float* __restrict__ gnw, const float* __restrict__ gnb,
    float* __restrict__ out)
{
    const int g  = blockIdx.x * 256 + threadIdx.x;
    const int n  = g >> 3;
    const int kl = g & 7;

    const int2   iv = *reinterpret_cast<const int2*>  (nidx + n*KK + kl*2);
    const float2 dv = *reinterpret_cast<const float2*>(nd2  + n*KK + kl*2);

    float at0[DD], at1[DD];
    {
        const float4* p0 = reinterpret_cast<const float4*>(yat + (long)iv.x*DD);
        const float4* p1 = reinterpret_cast<const float4*>(yat + (long)iv.y*DD);
        const float4 a = p0[0], b = p0[1], c = p0[2], d = p0[3];
        const float4 e = p1[0], f = p1[1], h = p1[2], i = p1[3];
        at0[0]=a.x; at0[1]=a.y; at0[2]=a.z; at0[3]=a.w;
        at0[4]=b.x; at0[5]=b.y; at0[6]=b.z; at0[7]=b.w;
        at0[8]=c.x; at0[9]=c.y; at0[10]=c.z; at0[11]=c.w;
        at0[12]=d.x; at0[13]=d.y; at0[14]=d.z; at0[15]=d.w;
        at1[0]=e.x; at1[1]=e.y; at1[2]=e.z; at1[3]=e.w;
        at1[4]=f.x; at1[5]=f.y; at1[6]=f.z; at1[7]=f.w;
        at1[8]=h.x; at1[9]=h.y; at1[10]=h.z; at1[11]=h.w;
        at1[12]=i.x; at1[13]=i.y; at1[14]=i.z; at1[15]=i.w;
    }

    float pe[DD];
    #pragma unroll
    for (int h = 0; h < DD; ++h) pe[h] = 1.0f;

    for (int L = 0; L < 3; ++L) {
        const float* wp = wpack + L*PK_LAY;

        float msg[DD];
        {
            const float4* bq = reinterpret_cast<const float4*>(b2 + L*DD);
            const float4 q0 = bq[0], q1 = bq[1], q2 = bq[2], q3 = bq[3];
            msg[0]=2.f*q0.x; msg[1]=2.f*q0.y; msg[2]=2.f*q0.z; msg[3]=2.f*q0.w;
            msg[4]=2.f*q1.x; msg[5]=2.f*q1.y; msg[6]=2.f*q1.z; msg[7]=2.f*q1.w;
            msg[8]=2.f*q2.x; msg[9]=2.f*q2.y; msg[10]=2.f*q2.z; msg[11]=2.f*q2.w;
            msg[12]=2.f*q3.x; msg[13]=2.f*q3.y; msg[14]=2.f*q3.z; msg[15]=2.f*q3.w;
        }

        #pragma unroll 1
        for (int o = 0; o < HH; ++o) {
            const float4* wx = reinterpret_cast<const float4*>(wp + PK_WX + o*20);
            const float4 x0 = wx[0], x1 = wx[1], x2 = wx[2], x3 = wx[3], x4 = wx[4];
            const float4* wb = reinterpret_cast<const float4*>(wp + PK_WB + o*16);
            const float4 y0 = wb[0], y1 = wb[1], y2 = wb[2], y3 = wb[3];
            const float4* wt = reinterpret_cast<const float4*>(wp + PK_WT + o*16);
            const float4 t0 = wt[0], t1 = wt[1], t2 = wt[2], t3 = wt[3];

            float bas = x4.x;                 // b1[o]
            DOT16(bas, pe, x0, x1, x2, x3);   // + pe . W1a[o]

            float u0 = fmaf(dv.x, x4.y, bas); // + dist*W1[o][32]
            DOT16(u0, at0, y0, y1, y2, y3);
            float u1 = fmaf(dv.y, x4.y, bas);
            DOT16(u1, at1, y0, y1, y2, y3);

            const float hs = fmaxf(u0, SLOPE*u0) + fmaxf(u1, SLOPE*u1);

            msg[0]  = fmaf(hs, t0.x, msg[0]);  msg[1]  = fmaf(hs, t0.y, msg[1]);
            msg[2]  = fmaf(hs, t0.z, msg[2]);  msg[3]  = fmaf(hs, t0.w, msg[3]);
            msg[4]  = fmaf(hs, t1.x, msg[4]);  msg[5]  = fmaf(hs, t1.y, msg[5]);
            msg[6]  = fmaf(hs, t1.z, msg[6]);  msg[7]  = fmaf(hs, t1.w, msg[7]);
            msg[8]  = fmaf(hs, t2.x, msg[8]);  msg[9]  = fmaf(hs, t2.y, msg[9]);
            msg[10] = fmaf(hs, t2.z, msg[10]); msg[11] = fmaf(hs, t2.w, msg[11]);
            msg[12] = fmaf(hs, t3.x, msg[12]); msg[13] = fmaf(hs, t3.y, msg[13]);
            msg[14] = fmaf(hs, t3.z, msg[14]); msg[15] = fmaf(hs, t3.w, msg[15]);
        }

        // sum partial msg over the 8 lanes of this point
        #pragma unroll
        for (int o = 0; o < DD; ++o) {
            msg[o] += __shfl_xor(msg[o], 1);
            msg[o] += __shfl_xor(msg[o], 2);
            msg[o] += __shfl_xor(msg[o], 4);
        }

        // GroupNorm(2,16) + leaky + residual (redundant per lane)
        const float4* gw = reinterpret_cast<const float4*>(gnw + L*DD);
        const float4* gb = reinterpret_cast<const float4*>(gnb + L*DD);
        const float4 gw0 = gw[0], gw1 = gw[1], gw2 = gw[2], gw3 = gw[3];
        const float4 gb0 = gb[0], gb1 = gb[1], gb2 = gb[2], gb3 = gb[3];
        const float gwa[DD] = { gw0.x,gw0.y,gw0.z,gw0.w, gw1.x,gw1.y,gw1.z,gw1.w,
                                gw2.x,gw2.y,gw2.z,gw2.w, gw3.x,gw3.y,gw3.z,gw3.w };
        const float gba[DD] = { gb0.x,gb0.y,gb0.z,gb0.w, gb1.x,gb1.y,gb1.z,gb1.w,
                                gb2.x,gb2.y,gb2.z,gb2.w, gb3.x,gb3.y,gb3.z,gb3.w };
        #pragma unroll
        for (int grp = 0; grp < 2; ++grp) {
            float mu = 0.0f;
            #pragma unroll
            for (int j = 0; j < 8; ++j) mu += msg[grp*8 + j];
            mu *= 0.125f;
            float var = 0.0f;
            #pragma unroll
            for (int j = 0; j < 8; ++j) { const float d = msg[grp*8 + j] - mu; var = fmaf(d, d, var); }
            var *= 0.125f;
            const float rs = rsqrtf(var + EPSGN);
            #pragma unroll
            for (int j = 0; j < 8; ++j) {
                const int c = grp*8 + j;
                const float v = (msg[c] - mu) * rs * gwa[c] + gba[c];
                pe[c] += fmaxf(v, SLOPE * v);
            }
        }
    }

    if (kl == 0) {
        float4* op = reinterpret_cast<float4*>(out + (long)n*DD);
        op[0] = make_float4(pe[0],  pe[1],  pe[2],  pe[3]);
        op[1] = make_float4(pe[4],  pe[5],  pe[6],  pe[7]);
        op[2] = make_float4(pe[8],  pe[9],  pe[10], pe[11]);
        op[3] = make_float4(pe[12], pe[13], pe[14], pe[15]);
    }
}

extern "C" void kernel_launch(void* const* d_in, const int* in_sizes, int n_in,
                              void* d_out, int out_size, void* d_ws, size_t ws_size,
                              hipStream_t stream) {
    const float* x   = (const float*)d_in[0];
    const float* y   = (const float*)d_in[1];
    const float* yat = (const float*)d_in[2];
    const int*   xb  = (const int*)  d_in[3];
    const int*   yb  = (const int*)  d_in[4];
    const float* W1  = (const float*)d_in[5];
    const float* b1  = (const float*)d_in[6];
    const float* W2  = (const float*)d_in[7];
    const float* b2  = (const float*)d_in[8];
    const float* gnw = (const float*)d_in[9];
    const float* gnb = (const float*)d_in[10];
    float* out = (float*)d_out;

    float* yfp    = (float*)((char*)d_ws + WS_YF);
    int*   seg    = (int*)  ((char*)d_ws + WS_SEG);
    float* wpack  = (float*)((char*)d_ws + WS_WP);
    int*   ws_idx = (int*)  ((char*)d_ws + WS_IDX);
    float* ws_d2  = (float*)((char*)d_ws + WS_D2);

    repack_kernel<<<16, 256, 0, stream>>>(W1, b1, W2, y, yb, wpack, yfp, seg);
    knn_kernel<<<N_PTS/4, 256, 0, stream>>>(x, xb, yfp, seg, y, ws_idx, ws_d2);
    mp_kernel<<<(N_PTS*8)/256, 256, 0, stream>>>(
        ws_idx, ws_d2, yat, wpack, b2, gnw, gnb, out);
}

// Round 9
// 90.118 us; speedup vs baseline: 1.4846x; 1.1487x over previous
//
#include <hip/hip_runtime.h>
#include <math.h>

#define N_PTS 20000
#define M_ATM 8000
#define DD    16
#define KK    16
#define HH    33
#define BB    4
#define EPSGN 1e-5f
#define SLOPE 0.2f
#define SLOTS 36          // 36*64 = 2304 candidate slots per batch
#define PSLOT 2304
#define SENT  0xFFFFFFFFu // > any real key (real off <= 2303 < 0xFFF)

// packed layout per layer (floats): wx[33][20] | wb[33][16] | wt[33][16]
#define PK_WX   0
#define PK_WB   660
#define PK_WT   1188
#define PK_LAY  1716

// ws layout (bytes)
#define WS_PAD   0                      // 4*2304*16 = 147456 (padded f32 atom table)
#define WS_SEG   147456                 // 8 ints
#define WS_WP    147520                 // 3*1716 floats -> ends 168112
#define WS_IDX   168128                 // N*K ints
#define WS_D2    (168128 + 1280000)     // N*K floats

// ---------------- repack: weights + padded f32 atom table + batch boundaries ----
__global__ void repack_kernel(const float* __restrict__ W1, const float* __restrict__ b1,
                              const float* __restrict__ W2,
                              const float* __restrict__ y, const int* __restrict__ yb,
                              float* __restrict__ wp, float* __restrict__ ypad,
                              int* __restrict__ seg)
{
    const int tid = blockIdx.x*256 + threadIdx.x;
    const int stride = gridDim.x*256;

    for (int i = tid; i < 3*PK_LAY; i += stride) {
        const int L = i / PK_LAY, r = i % PK_LAY;
        float v;
        if (r < PK_WB) {                    // wx[o][20] = W1a(16) | b1 | w_dist | pad2
            const int o = r / 20, c = r % 20;
            if      (c < 16)  v = W1[(L*HH + o)*HH + c];
            else if (c == 16) v = b1[L*HH + o];
            else if (c == 17) v = W1[(L*HH + o)*HH + 32];
            else              v = 0.0f;
        } else if (r < PK_WT) {             // wb[o][16] = W1[o][16..31]
            const int q = r - PK_WB, o = q / 16, c = q % 16;
            v = W1[(L*HH + o)*HH + 16 + c];
        } else {                            // wt[o][16] = W2[d][o] transposed
            const int q = r - PK_WT, o = q / 16, d = q % 16;
            v = W2[(L*DD + d)*HH + o];
        }
        wp[i] = v;
    }

    // padded candidate table: [b][slot] = (-2y0,-2y1,-2y2,|y|^2), pad = +inf
    for (int p = tid; p < BB*PSLOT; p += stride) {
        const int b = p / PSLOT, o = p % PSLOT;
        int l = 0, r = M_ATM;
        while (l < r) { int m = (l+r) >> 1; if (yb[m] <  b) l = m+1; else r = m; }
        const int lo = l;
        l = 0; r = M_ATM;
        while (l < r) { int m = (l+r) >> 1; if (yb[m] <= b) l = m+1; else r = m; }
        const int hi = l;
        float4 v;
        const int j = lo + o;
        if (j < hi) {
            const double y0 = (double)y[j*3+0];
            const double y1 = (double)y[j*3+1];
            const double y2 = (double)y[j*3+2];
            v = make_float4((float)(-2.0*y0), (float)(-2.0*y1), (float)(-2.0*y2),
                            (float)(y0*y0 + y1*y1 + y2*y2));
        } else {
            v = make_float4(0.0f, 0.0f, 0.0f, __builtin_inff());
        }
        reinterpret_cast<float4*>(ypad)[p] = v;
    }

    for (int j = tid; j < M_ATM; j += stride) {
        const int bcur  = yb[j];
        const int bprev = (j == 0) ? -1 : yb[j-1];
        for (int t = bprev+1; t <= bcur; ++t) seg[t] = j;
        if (j == M_ATM-1) { for (int t = bcur+1; t <= BB; ++t) seg[t] = M_ATM; }
    }
}

__device__ __forceinline__ unsigned wave_min_u32(unsigned v) {
    #define SW(OFF) { const unsigned o = (unsigned)__builtin_amdgcn_ds_swizzle((int)v, OFF); v = (o < v) ? o : v; }
    SW(0x041F) SW(0x081F) SW(0x101F) SW(0x201F) SW(0x401F)
    #undef SW
    { const unsigned o = (unsigned)__shfl_xor((int)v, 32); v = (o < v) ? o : v; }
    return v;
}

// ---------------- KNN: one WAVE per point, u32 truncated-key selection ----------
// key = (f32bits(d2) & 0xFFFFF000) | offset.  Unique keys; winner lane = key&63.
// Top-16 set by truncated order + margin extras; exact f64 rank-select finalize.
// Output ORDER is free: mp sums over k (permutation-invariant).
__global__ __launch_bounds__(256) void knn_kernel(
    const float* __restrict__ x, const int* __restrict__ xb,
    const float* __restrict__ ypad, const int* __restrict__ seg,
    const float* __restrict__ yg,
    int* __restrict__ out_idx, float* __restrict__ out_d2)
{
    const int wv   = threadIdx.x >> 6;
    const int lane = threadIdx.x & 63;
    const int n    = blockIdx.x * 4 + wv;

    const float xf0 = x[n*3+0], xf1 = x[n*3+1], xf2 = x[n*3+2];
    const float sxf = fmaf(xf0, xf0, fmaf(xf1, xf1, xf2*xf2));
    const int b  = xb[n];
    const int lo = seg[b];
    const float4* __restrict__ base =
        reinterpret_cast<const float4*>(ypad) + b*PSLOT + lane;

    // per-lane sorted top-4 keys via unconditional min/max network
    unsigned m0 = SENT, m1 = SENT, m2 = SENT, m3 = SENT;
    #pragma unroll
    for (int s = 0; s < SLOTS; ++s) {
        const float4 q = base[64*s];
        float dd = fmaf(xf2, q.z, fmaf(xf1, q.y, fmaf(xf0, q.x, sxf + q.w)));
        dd = fmaxf(dd, 0.0f);
        const unsigned kb = (__float_as_uint(dd) & 0xFFFFF000u)
                          | (unsigned)(lane | (s << 6));
        const unsigned a0 = min(m0, kb), c0 = max(m0, kb);
        const unsigned a1 = min(m1, c0), c1 = max(m1, c0);
        const unsigned a2 = min(m2, c1), c2 = max(m2, c1);
        const unsigned a3 = min(m3, c2);
        m0 = a0; m1 = a1; m2 = a2; m3 = a3;
    }

    unsigned long long cmask = 0ull;   // consumed slots (for rare rebuild)
    unsigned res_key = 0, h16 = 0;

    #define POPWIN(H)                                                         \
        if (lane == ((H) & 63u)) {                                            \
            cmask |= 1ull << (((H) >> 6) & 63u);                              \
            m0 = m1; m1 = m2; m2 = m3; m3 = SENT;                             \
            if (m0 == SENT) {                                                 \
                _Pragma("unroll 1")                                           \
                for (int s2 = 0; s2 < SLOTS; ++s2) {                          \
                    const float4 q2 = base[64*s2];                            \
                    float d2f = fmaf(xf2, q2.z, fmaf(xf1, q2.y,               \
                                 fmaf(xf0, q2.x, sxf + q2.w)));               \
                    d2f = fmaxf(d2f, 0.0f);                                   \
                    unsigned kb2 = (__float_as_uint(d2f) & 0xFFFFF000u)       \
                                 | (unsigned)(lane | (s2 << 6));              \
                    if ((cmask >> s2) & 1ull) kb2 = SENT;                     \
                    const unsigned a0 = min(m0, kb2), c0 = max(m0, kb2);      \
                    const unsigned a1 = min(m1, c0), c1 = max(m1, c0);        \
                    const unsigned a2 = min(m2, c1), c2 = max(m2, c1);        \
                    const unsigned a3 = min(m3, c2);                          \
                    m0 = a0; m1 = a1; m2 = a2; m3 = a3;                       \
                }                                                             \
            }                                                                 \
        }

    for (int r = 0; r < KK; ++r) {
        const unsigned h = wave_min_u32(m0);   // wave-uniform winner key
        if (lane == r) res_key = h;
        h16 = h;
        POPWIN(h)
    }

    // margin extras: truncation (2^-11 rel) + f32 eval error coverage
    int e = 0;
    {
        const float d16t = __uint_as_float(h16 & 0xFFFFF000u);
        const unsigned limbits = __float_as_uint(fmaf(d16t, 1.0025f, 0.01f));
        while (e < 8) {
            const unsigned h = wave_min_u32(m0);
            if ((h & 0xFFFFF000u) > limbits) break;
            if (lane == KK + e) res_key = h;
            POPWIN(h)
            ++e;
        }
    }
    #undef POPWIN

    // finalize: exact f64 distances for the 16+e survivors
    const int nact = KK + e;
    const bool have = (lane < nact);
    const unsigned off = res_key & 0xFFFu;
    double dd64 = 0.0;
    if (have) {
        const int j = lo + (int)off;
        const double yy0 = (double)yg[j*3+0];
        const double yy1 = (double)yg[j*3+1];
        const double yy2 = (double)yg[j*3+2];
        const double xd0 = (double)xf0, xd1 = (double)xf1, xd2 = (double)xf2;
        const double sxd = fma(xd0, xd0, fma(xd1, xd1, xd2*xd2));
        const double syd = fma(yy0, yy0, fma(yy1, yy1, yy2*yy2));
        dd64 = fma(xd2, -2.0*yy2, fma(xd1, -2.0*yy1, fma(xd0, -2.0*yy0, sxd + syd)));
        dd64 = fmax(dd64, 0.0);
    }

    if (e == 0) {
        if (have) {
            out_idx[n*KK + lane] = lo + (int)off;
            out_d2 [n*KK + lane] = (float)dd64;
        }
    } else {
        // exact u64 keys (f64 bits, low 12 -> offset); pick true top-16 subset
        const unsigned long long fkey = have
            ? (((unsigned long long)__double_as_longlong(dd64) & ~0xFFFull) | off)
            : 0xFFFFFFFFFFFFFFFFull;
        int rank = 0;
        #pragma unroll 1
        for (int t = 0; t < nact; ++t) {
            const unsigned klo = (unsigned)__builtin_amdgcn_readlane((int)(unsigned)fkey, t);
            const unsigned khi = (unsigned)__builtin_amdgcn_readlane((int)(unsigned)(fkey >> 32), t);
            const unsigned long long kt = ((unsigned long long)khi << 32) | klo;
            rank += (kt < fkey) ? 1 : 0;
        }
        if (have && rank < KK) {
            out_idx[n*KK + rank] = lo + (int)off;
            out_d2 [n*KK + rank] = (float)dd64;
        }
    }
}

// ---------------- MP: 8 lanes/point, 2 k's/lane, rolled o-loop, 2-chain dots ----
#define DOT16(res, A, q0, q1, q2, q3) {                                 \
    float _e = res, _o = 0.0f;                                          \
    _e = fmaf(A[0],  q0.x, _e); _o = fmaf(A[1],  q0.y, _o);             \
    _e = fmaf(A[2],  q0.z, _e); _o = fmaf(A[3],  q0.w, _o);             \
    _e = fmaf(A[4],  q1.x, _e); _o = fmaf(A[5],  q1.y, _o);             \
    _e = fmaf(A[6],  q1.z, _e); _o = fmaf(A[7],  q1.w, _o);             \
    _e = fmaf(A[8],  q2.x, _e); _o = fmaf(A[9],  q2.y, _o);             \
    _e = fmaf(A[10], q2.z, _e); _o = fmaf(A[11], q2.w, _o);             \
    _e = fmaf(A[12], q3.x, _e); _o = fmaf(A[13], q3.y, _o);             \
    _e = fmaf(A[14], q3.z, _e); _o = fmaf(A[15], q3.w, _o);             \
    res = _e + _o; }

__global__ __launch_bounds__(256) void mp_kernel(
    const int*   __restrict__ nidx, const float* __restrict__ nd2,
    const float* __restrict__ yat,  const float* __restrict__ wpack,
    const float* __restrict__ b2,
    const float* __restrict__ gnw, const float* __restrict__ gnb,
    float* __restrict__ out)
{
    const int g  = blockIdx.x * 256 + threadIdx.x;
    const int n  = g >> 3;
    const int kl = g & 7;

    const int2   iv = *reinterpret_cast<const int2*>  (nidx + n*KK + kl*2);
    const float2 dv = *reinterpret_cast<const float2*>(nd2  + n*KK + kl*2);

    float at0[DD], at1[DD];
    {
        const float4* p0 = reinterpret_cast<const float4*>(yat + (long)iv.x*DD);
        const float4* p1 = reinterpret_cast<const float4*>(yat + (long)iv.y*DD);
        const float4 a = p0[0], b = p0[1], c = p0[2], d = p0[3];
        const float4 e = p1[0], f = p1[1], h = p1[2], i = p1[3];
        at0[0]=a.x; at0[1]=a.y; at0[2]=a.z; at0[3]=a.w;
        at0[4]=b.x; at0[5]=b.y; at0[6]=b.z; at0[7]=b.w;
        at0[8]=c.x; at0[9]=c.y; at0[10]=c.z; at0[11]=c.w;
        at0[12]=d.x; at0[13]=d.y; at0[14]=d.z; at0[15]=d.w;
        at1[0]=e.x; at1[1]=e.y; at1[2]=e.z; at1[3]=e.w;
        at1[4]=f.x; at1[5]=f.y; at1[6]=f.z; at1[7]=f.w;
        at1[8]=h.x; at1[9]=h.y; at1[10]=h.z; at1[11]=h.w;
        at1[12]=i.x; at1[13]=i.y; at1[14]=i.z; at1[15]=i.w;
    }

    float pe[DD];
    #pragma unroll
    for (int h = 0; h < DD; ++h) pe[h] = 1.0f;

    for (int L = 0; L < 3; ++L) {
        const float* wp = wpack + L*PK_LAY;

        float msg[DD];
        {
            const float4* bq = reinterpret_cast<const float4*>(b2 + L*DD);
            const float4 q0 = bq[0], q1 = bq[1], q2 = bq[2], q3 = bq[3];
            msg[0]=2.f*q0.x; msg[1]=2.f*q0.y; msg[2]=2.f*q0.z; msg[3]=2.f*q0.w;
            msg[4]=2.f*q1.x; msg[5]=2.f*q1.y; msg[6]=2.f*q1.z; msg[7]=2.f*q1.w;
            msg[8]=2.f*q2.x; msg[9]=2.f*q2.y; msg[10]=2.f*q2.z; msg[11]=2.f*q2.w;
            msg[12]=2.f*q3.x; msg[13]=2.f*q3.y; msg[14]=2.f*q3.z; msg[15]=2.f*q3.w;
        }

        #pragma unroll 1
        for (int o = 0; o < HH; ++o) {
            const float4* wx = reinterpret_cast<const float4*>(wp + PK_WX + o*20);
            const float4 x0 = wx[0], x1 = wx[1], x2 = wx[2], x3 = wx[3], x4 = wx[4];
            const float4* wb = reinterpret_cast<const float4*>(wp + PK_WB + o*16);
            const float4 y0 = wb[0], y1 = wb[1], y2 = wb[2], y3 = wb[3];
            const float4* wt = reinterpret_cast<const float4*>(wp + PK_WT + o*16);
            const float4 t0 = wt[0], t1 = wt[1], t2 = wt[2], t3 = wt[3];

            float bas = x4.x;                 // b1[o]
            DOT16(bas, pe, x0, x1, x2, x3);   // + pe . W1a[o]

            float u0 = fmaf(dv.x, x4.y, bas); // + dist*W1[o][32]
            DOT16(u0, at0, y0, y1, y2, y3);
            float u1 = fmaf(dv.y, x4.y, bas);
            DOT16(u1, at1, y0, y1, y2, y3);

            const float hs = fmaxf(u0, SLOPE*u0) + fmaxf(u1, SLOPE*u1);

            msg[0]  = fmaf(hs, t0.x, msg[0]);  msg[1]  = fmaf(hs, t0.y, msg[1]);
            msg[2]  = fmaf(hs, t0.z, msg[2]);  msg[3]  = fmaf(hs, t0.w, msg[3]);
            msg[4]  = fmaf(hs, t1.x, msg[4]);  msg[5]  = fmaf(hs, t1.y, msg[5]);
            msg[6]  = fmaf(hs, t1.z, msg[6]);  msg[7]  = fmaf(hs, t1.w, msg[7]);
            msg[8]  = fmaf(hs, t2.x, msg[8]);  msg[9]  = fmaf(hs, t2.y, msg[9]);
            msg[10] = fmaf(hs, t2.z, msg[10]); msg[11] = fmaf(hs, t2.w, msg[11]);
            msg[12] = fmaf(hs, t3.x, msg[12]); msg[13] = fmaf(hs, t3.y, msg[13]);
            msg[14] = fmaf(hs, t3.z, msg[14]); msg[15] = fmaf(hs, t3.w, msg[15]);
        }

        // sum partial msg over the 8 lanes of this point
        #pragma unroll
        for (int o = 0; o < DD; ++o) {
            msg[o] += __shfl_xor(msg[o], 1);
            msg[o] += __shfl_xor(msg[o], 2);
            msg[o] += __shfl_xor(msg[o], 4);
        }

        // GroupNorm(2,16) + leaky + residual (redundant per lane)
        const float4* gw = reinterpret_cast<const float4*>(gnw + L*DD);
        const float4* gb = reinterpret_cast<const float4*>(gnb + L*DD);
        const float4 gw0 = gw[0], gw1 = gw[1], gw2 = gw[2], gw3 = gw[3];
        const float4 gb0 = gb[0], gb1 = gb[1], gb2 = gb[2], gb3 = gb[3];
        const float gwa[DD] = { gw0.x,gw0.y,gw0.z,gw0.w, gw1.x,gw1.y,gw1.z,gw1.w,
                                gw2.x,gw2.y,gw2.z,gw2.w, gw3.x,gw3.y,gw3.z,gw3.w };
        const float gba[DD] = { gb0.x,gb0.y,gb0.z,gb0.w, gb1.x,gb1.y,gb1.z,gb1.w,
                                gb2.x,gb2.y,gb2.z,gb2.w, gb3.x,gb3.y,gb3.z,gb3.w };
        #pragma unroll
        for (int grp = 0; grp < 2; ++grp) {
            float mu = 0.0f;
            #pragma unroll
            for (int j = 0; j < 8; ++j) mu += msg[grp*8 + j];
            mu *= 0.125f;
            float var = 0.0f;
            #pragma unroll
            for (int j = 0; j < 8; ++j) { const float d = msg[grp*8 + j] - mu; var = fmaf(d, d, var); }
            var *= 0.125f;
            const float rs = rsqrtf(var + EPSGN);
            #pragma unroll
            for (int j = 0; j < 8; ++j) {
                const int c = grp*8 + j;
                const float v = (msg[c] - mu) * rs * gwa[c] + gba[c];
                pe[c] += fmaxf(v, SLOPE * v);
            }
        }
    }

    if (kl == 0) {
        float4* op = reinterpret_cast<float4*>(out + (long)n*DD);
        op[0] = make_float4(pe[0],  pe[1],  pe[2],  pe[3]);
        op[1] = make_float4(pe[4],  pe[5],  pe[6],  pe[7]);
        op[2] = make_float4(pe[8],  pe[9],  pe[10], pe[11]);
        op[3] = make_float4(pe[12], pe[13], pe[14], pe[15]);
    }
}

extern "C" void kernel_launch(void* const* d_in, const int* in_sizes, int n_in,
                              void* d_out, int out_size, void* d_ws, size_t ws_size,
                              hipStream_t stream) {
    const float* x   = (const float*)d_in[0];
    const float* y   = (const float*)d_in[1];
    const float* yat = (const float*)d_in[2];
    const int*   xb  = (const int*)  d_in[3];
    const int*   yb  = (const int*)  d_in[4];
    const float* W1  = (const float*)d_in[5];
    const float* b1  = (const float*)d_in[6];
    const float* W2  = (const float*)d_in[7];
    const float* b2  = (const float*)d_in[8];
    const float* gnw = (const float*)d_in[9];
    const float* gnb = (const float*)d_in[10];
    float* out = (float*)d_out;

    float* ypad   = (float*)((char*)d_ws + WS_PAD);
    int*   seg    = (int*)  ((char*)d_ws + WS_SEG);
    float* wpack  = (float*)((char*)d_ws + WS_WP);
    int*   ws_idx = (int*)  ((char*)d_ws + WS_IDX);
    float* ws_d2  = (float*)((char*)d_ws + WS_D2);

    repack_kernel<<<16, 256, 0, stream>>>(W1, b1, W2, y, yb, wpack, ypad, seg);
    knn_kernel<<<N_PTS/4, 256, 0, stream>>>(x, xb, ypad, seg, y, ws_idx, ws_d2);
    mp_kernel<<<(N_PTS*8)/256, 256, 0, stream>>>(
        ws_idx, ws_d2, yat, wpack, b2, gnw, gnb, out);
}